// Round 1
// baseline (41.108 us; speedup 1.0000x reference)
//
#include <hip/hip_runtime.h>
#include <math.h>

// Problem constants (from reference)
constexpr int Wd = 320, Ht = 240;
constexpr int NB = 16, NV = 48, NBATCH = 16;
constexpr float BG = 100.0f, CMIN = 0.01f;

constexpr int QPI = Wd * Ht / 4;   // 19200 quad-pixels (float4 units) per image
constexpr int BPB = QPI / 256;     // 75 blocks per batch image

__global__ __launch_bounds__(256) void render_kernel(
    const float* __restrict__ tmats,   // [B][NB][4][4] f32
    const float* __restrict__ verts,   // [NV][4] f32 (w component == 1)
    const float* __restrict__ rads,    // [NV] f32
    const int*   __restrict__ bidx,    // [NV] i32
    float* __restrict__ out)           // part_maps [B][NV][H][W] then depth_maps [B][H][W]
{
    __shared__ float sX[NV], sY[NV], sZ[NV], sR2[NV];

    const int tid = threadIdx.x;
    const int b   = blockIdx.x / BPB;

    // --- skinning: 48 tiny matvecs, sequential-rounded to match numpy einsum ---
    if (tid < NV) {
        const int v  = tid;
        const int bi = bidx[v];
        const float* T = tmats + (size_t)(b * NB + bi) * 16;
        const float vx = verts[4 * v + 0];
        const float vy = verts[4 * v + 1];
        const float vz = verts[4 * v + 2];
        const float vw = verts[4 * v + 3];

        float a0 = __fmul_rn(T[0], vx);
        a0 = __fadd_rn(a0, __fmul_rn(T[1], vy));
        a0 = __fadd_rn(a0, __fmul_rn(T[2], vz));
        a0 = __fadd_rn(a0, __fmul_rn(T[3], vw));
        sX[v] = a0;

        float a1 = __fmul_rn(T[4], vx);
        a1 = __fadd_rn(a1, __fmul_rn(T[5], vy));
        a1 = __fadd_rn(a1, __fmul_rn(T[6], vz));
        a1 = __fadd_rn(a1, __fmul_rn(T[7], vw));
        sY[v] = a1;

        float a2 = __fmul_rn(T[8], vx);
        a2 = __fadd_rn(a2, __fmul_rn(T[9], vy));
        a2 = __fadd_rn(a2, __fmul_rn(T[10], vz));
        a2 = __fadd_rn(a2, __fmul_rn(T[11], vw));
        sZ[v] = a2;

        const float r = rads[v];
        sR2[v] = __fmul_rn(r, r);
    }
    __syncthreads();

    // --- per-thread: 4 consecutive w pixels of one row of one batch image ---
    const int q  = (blockIdx.x % BPB) * 256 + tid;  // 0..19199
    const int h  = q / (Wd / 4);
    const int w0 = (q % (Wd / 4)) * 4;

    // exact grid coords: (w-160)*0.9375 and (h-120)*1.25 are exactly representable
    const float yg = __fmul_rn((float)(h - Ht / 2), 1.25f);
    float xg[4], dmin[4];
#pragma unroll
    for (int k = 0; k < 4; ++k) {
        xg[k]   = __fmul_rn((float)(w0 + k - Wd / 2), 0.9375f);
        dmin[k] = INFINITY;
    }

    const size_t pix  = (size_t)h * Wd + w0;
    float* part = out + (size_t)b * NV * Ht * Wd + pix;

    for (int v = 0; v < NV; ++v) {
        const float X = sX[v], Y = sY[v], Z = sZ[v], R2 = sR2[v];
        const float dy  = __fsub_rn(yg, Y);
        const float dy2 = __fmul_rn(dy, dy);

        float o[4];
#pragma unroll
        for (int k = 0; k < 4; ++k) {
            const float dx  = __fsub_rn(xg[k], X);
            const float dx2 = __fmul_rn(dx, dx);
            // numpy order: (r2 - dx2) - dy2, each individually rounded, no FMA
            const float sq  = __fsub_rn(__fsub_rn(R2, dx2), dy2);
            const float s   = __fsqrt_rn(fmaxf(sq, CMIN));  // IEEE sqrt = np.sqrt
            const float val = (sq > CMIN) ? __fsub_rn(Z, s) : BG;
            o[k]    = val;
            dmin[k] = fminf(dmin[k], val);
        }
        *reinterpret_cast<float4*>(part + (size_t)v * (Ht * Wd)) =
            make_float4(o[0], o[1], o[2], o[3]);
    }

    float* depth = out + (size_t)NBATCH * NV * Ht * Wd + (size_t)b * Ht * Wd + pix;
    *reinterpret_cast<float4*>(depth) = make_float4(dmin[0], dmin[1], dmin[2], dmin[3]);
}

extern "C" void kernel_launch(void* const* d_in, const int* in_sizes, int n_in,
                              void* d_out, int out_size, void* d_ws, size_t ws_size,
                              hipStream_t stream) {
    const float* tmats = (const float*)d_in[0];  // (16,16,4,4)
    const float* verts = (const float*)d_in[1];  // (48,4)
    const float* rads  = (const float*)d_in[2];  // (48,)
    const int*   bidx  = (const int*)d_in[3];    // (48,)
    float* out = (float*)d_out;

    dim3 grid(NBATCH * BPB);  // 1200 blocks
    dim3 block(256);
    render_kernel<<<grid, block, 0, stream>>>(tmats, verts, rads, bidx, out);
}